// Round 5
// baseline (184.201 us; speedup 1.0000x reference)
//
#include <hip/hip_runtime.h>

#define BB 2
#define NN 2048
#define EE 768
#define HH 12
#define DD 64
#define MM (BB*NN)      // 4096
#define E3 (3*EE)       // 2304
// 1/sqrt(768) * log2(e): scores in log2 domain -> P = exp2(s)
#define QSCALE 0.05205877280961602f

typedef __bf16 bf16x8 __attribute__((ext_vector_type(8)));
typedef float  f32x4  __attribute__((ext_vector_type(4)));
typedef unsigned short u16x8 __attribute__((ext_vector_type(8)));

#define MFMA(a,b,c) __builtin_amdgcn_mfma_f32_16x16x32_bf16(a,b,c,0,0,0)

__device__ __forceinline__ unsigned short f2bf(float f) {
    unsigned int u = __float_as_uint(f);
    u += 0x7FFFu + ((u >> 16) & 1u);     // round-to-nearest-even
    return (unsigned short)(u >> 16);
}

__device__ __forceinline__ bf16x8 as_bf16x8(u16x8 v) {
    union { u16x8 u; bf16x8 b; } c; c.u = v; return c.b;
}

typedef __attribute__((address_space(3))) unsigned int as3u32;
typedef __attribute__((address_space(1))) unsigned int as1u32;
__device__ __forceinline__ void gll16(const void* g, void* l) {
    // lane i deposits its 16B at lds_base + i*16 (wave-uniform dest base)
    __builtin_amdgcn_global_load_lds((const as1u32*)(uintptr_t)g,
                                     (as3u32*)(unsigned int)(uintptr_t)l, 16, 0, 0);
}

// ---------------------------------------------------------------------------
// fused f32 -> bf16 cast of x, w_qkv, w_o (contiguous dsts in ws)
// ---------------------------------------------------------------------------
#define XB4 786432   // (MM*EE)/4
#define WQ4 442368   // (E3*EE)/4
#define WO4 147456   // (EE*EE)/4
__global__ __launch_bounds__(256)
void cast3(const float* __restrict__ x, const float* __restrict__ wq,
           const float* __restrict__ wo, unsigned short* __restrict__ dst) {
    int i = blockIdx.x * 256 + threadIdx.x;
    const float* src;
    int off;
    if (i < XB4)            { src = x;  off = i; }
    else if (i < XB4+WQ4)   { src = wq; off = i - XB4; }
    else                    { src = wo; off = i - XB4 - WQ4; }
    float4 v = ((const float4*)src)[off];
    ushort4 o;
    o.x = f2bf(v.x); o.y = f2bf(v.y); o.z = f2bf(v.z); o.w = f2bf(v.w);
    ((ushort4*)dst)[i] = o;
}

// ---------------------------------------------------------------------------
// QKV GEMM: 128x64 tile, BK=32, 4 waves, wave tile 64x32 (4x2 frags).
// Grid (32,36) = 1152 blocks = 4.5 blocks/CU.
// Each block covers exactly one (h,t) 64-col section.
// Scatter: q (scaled) [B][H][N][D], k [B][H][N][D], v transposed [B][H][D][N].
// ---------------------------------------------------------------------------
__global__ __launch_bounds__(256)
void gemm_qkv(const unsigned short* __restrict__ A, const unsigned short* __restrict__ W,
              const float* __restrict__ bias,
              unsigned short* __restrict__ o0, unsigned short* __restrict__ o1,
              unsigned short* __restrict__ o2)
{
    __shared__ unsigned short As[128 * 32];   // 8 KB
    __shared__ unsigned short Bs[64 * 32];    // 4 KB

    const int tid = threadIdx.x;
    const int l = tid & 63;
    const int w = tid >> 6;
    const int m0 = blockIdx.x * 128;
    const int c0 = blockIdx.y * 64;
    const int wm = (w >> 1) * 64;
    const int wn = (w & 1) * 32;

    // staging: 12 chunks of 16 rows x 32 k (8 A + 4 B); wave stages 3w..3w+2
    const unsigned short* s_src[3];
    unsigned short* s_dst[3];
    #pragma unroll
    for (int s = 0; s < 3; ++s) {
        const int ch = 3*w + s;
        if (ch < 8) {
            s_src[s] = A + (size_t)(m0 + ch*16 + (l>>2)) * EE + (l&3)*8;
            s_dst[s] = &As[ch*512];
        } else {
            s_src[s] = W + (size_t)(c0 + (ch-8)*16 + (l>>2)) * EE + (l&3)*8;
            s_dst[s] = &Bs[(ch-8)*512];
        }
    }

    const f32x4 zero4 = {0.f, 0.f, 0.f, 0.f};
    f32x4 acc[4][2];
    #pragma unroll
    for (int i = 0; i < 4; ++i)
        #pragma unroll
        for (int j = 0; j < 2; ++j) acc[i][j] = zero4;

    for (int k0 = 0; k0 < EE; k0 += 32) {
        __syncthreads();
        #pragma unroll
        for (int s = 0; s < 3; ++s) gll16(s_src[s] + k0, s_dst[s]);
        __syncthreads();

        bf16x8 af[4], bf[2];
        #pragma unroll
        for (int i = 0; i < 4; ++i)
            af[i] = *(const bf16x8*)&As[(wm + 16*i + (l&15))*32 + (l>>4)*8];
        #pragma unroll
        for (int j = 0; j < 2; ++j)
            bf[j] = *(const bf16x8*)&Bs[(wn + 16*j + (l&15))*32 + (l>>4)*8];
        #pragma unroll
        for (int i = 0; i < 4; ++i)
            #pragma unroll
            for (int j = 0; j < 2; ++j)
                acc[i][j] = MFMA(af[i], bf[j], acc[i][j]);
    }

    // epilogue: C/D col = l&15, row = (l>>4)*4 + r. Block = one (h,t) section.
    const int sec = c0 >> 6;               // = hh*3 + tt
    const int hh = sec / 3;
    const int tt = sec - hh*3;
    #pragma unroll
    for (int j = 0; j < 2; ++j) {
        const int col = c0 + wn + 16*j + (l&15);
        const int dcol = wn + 16*j + (l&15);   // 0..63 within section
        const float bj = bias[col];
        #pragma unroll
        for (int i = 0; i < 4; ++i) {
            const int row0 = m0 + wm + 16*i + (l>>4)*4;
            const int b = row0 >> 11;
            const int n = row0 & (NN - 1);
            if (tt == 2) {
                ushort4 pk;
                pk.x = f2bf(acc[i][j][0] + bj);
                pk.y = f2bf(acc[i][j][1] + bj);
                pk.z = f2bf(acc[i][j][2] + bj);
                pk.w = f2bf(acc[i][j][3] + bj);
                *(ushort4*)&o2[(((size_t)b*HH + hh)*DD + dcol)*NN + n] = pk;
            } else {
                unsigned short* dst = (tt == 0) ? o0 : o1;
                #pragma unroll
                for (int r = 0; r < 4; ++r) {
                    float val = acc[i][j][r] + bj;
                    if (tt == 0) val *= QSCALE;
                    dst[(((size_t)b*HH + hh)*NN + n + r)*DD + dcol] = f2bf(val);
                }
            }
        }
    }
}

// ---------------------------------------------------------------------------
// Output GEMM: 64x64 tile, BK=32, 4 waves, wave tile 32x32 (2x2 frags).
// Grid (64,12) = 768 blocks = 3 blocks/CU.
// ---------------------------------------------------------------------------
__global__ __launch_bounds__(256)
void gemm_out(const unsigned short* __restrict__ A, const unsigned short* __restrict__ W,
              const float* __restrict__ bias, float* __restrict__ of)
{
    __shared__ unsigned short As[64 * 32];    // 4 KB
    __shared__ unsigned short Bs[64 * 32];    // 4 KB

    const int tid = threadIdx.x;
    const int l = tid & 63;
    const int w = tid >> 6;
    const int m0 = blockIdx.x * 64;
    const int c0 = blockIdx.y * 64;
    const int wm = (w >> 1) * 32;
    const int wn = (w & 1) * 32;

    // staging: 8 chunks of 16 rows x 32 k (4 A + 4 B); wave stages 2w, 2w+1
    const unsigned short* s_src[2];
    unsigned short* s_dst[2];
    #pragma unroll
    for (int s = 0; s < 2; ++s) {
        const int ch = 2*w + s;
        if (ch < 4) {
            s_src[s] = A + (size_t)(m0 + ch*16 + (l>>2)) * EE + (l&3)*8;
            s_dst[s] = &As[ch*512];
        } else {
            s_src[s] = W + (size_t)(c0 + (ch-4)*16 + (l>>2)) * EE + (l&3)*8;
            s_dst[s] = &Bs[(ch-4)*512];
        }
    }

    const f32x4 zero4 = {0.f, 0.f, 0.f, 0.f};
    f32x4 acc[2][2];
    #pragma unroll
    for (int i = 0; i < 2; ++i)
        #pragma unroll
        for (int j = 0; j < 2; ++j) acc[i][j] = zero4;

    for (int k0 = 0; k0 < EE; k0 += 32) {
        __syncthreads();
        #pragma unroll
        for (int s = 0; s < 2; ++s) gll16(s_src[s] + k0, s_dst[s]);
        __syncthreads();

        bf16x8 af[2], bf[2];
        #pragma unroll
        for (int i = 0; i < 2; ++i)
            af[i] = *(const bf16x8*)&As[(wm + 16*i + (l&15))*32 + (l>>4)*8];
        #pragma unroll
        for (int j = 0; j < 2; ++j)
            bf[j] = *(const bf16x8*)&Bs[(wn + 16*j + (l&15))*32 + (l>>4)*8];
        #pragma unroll
        for (int i = 0; i < 2; ++i)
            #pragma unroll
            for (int j = 0; j < 2; ++j)
                acc[i][j] = MFMA(af[i], bf[j], acc[i][j]);
    }

    #pragma unroll
    for (int j = 0; j < 2; ++j) {
        const int col = c0 + wn + 16*j + (l&15);
        const float bj = bias[col];
        #pragma unroll
        for (int i = 0; i < 2; ++i) {
            #pragma unroll
            for (int r = 0; r < 4; ++r) {
                const int row = m0 + wm + 16*i + (l>>4)*4 + r;
                of[(size_t)row * EE + col] = acc[i][j][r] + bj;
            }
        }
    }
}

// ---------------------------------------------------------------------------
// MFMA flash attention, v5: 2 WAVES x 32 Q — halve LDS read traffic.
// Diagnosis: v0-v4 all ~56us with MfmaUtil 18 / VALUBusy 39 / HBM 3.5% /
// conflicts 0 -> LDS-BW-bound: 4 waves each re-read the full K/V tile
// (6.3 MB/CU of ds_read_b128 = ~38us at 85 B/cyc). Fix: each wave now
// owns 32 q-rows (2 q-groups), so every K/V fragment ds_read feeds TWO
// MFMAs. Block = 128 threads (2 waves), 64 q, grid 768 (even 3/CU).
// Per-CU LDS reads halve to ~3.1 MB. MFMA/exp2 totals unchanged.
// Keeps: P-in-registers (sigma-permuted V blocks), K/V XOR swizzle,
// async-STAGE pipeline (raw s_barrier + lgkmcnt, no vmcnt drain).
// Staging (128 thr): srow = tid>>1 (64 rows), sc = tid&1 (64 B = 4 chunks).
// ---------------------------------------------------------------------------
struct KVT { u16x8 k[2][4]; u16x8 v[2][4]; };

__global__ __launch_bounds__(128)
void attn_mfma(const unsigned short* __restrict__ Q, const unsigned short* __restrict__ K,
               const unsigned short* __restrict__ Vt_g, unsigned short* __restrict__ ctx)
{
    __shared__ unsigned short Ks[2 * 64 * 64];       // 16 KB (two halves)
    __shared__ unsigned short Vt[2 * 64 * 64];       // 16 KB, key-permuted blocks

    const int tid = threadIdx.x;
    const int l = tid & 63;
    const int w = tid >> 6;              // wave 0/1 -> q rows [w*32, w*32+32)
    const int quad = l >> 4;
    const int lc = l & 15;
    const int x7 = lc & 7;

    const int id = blockIdx.x;
    const int bh = id % 24;              // b*HH + h
    const int bq = id / 24;              // q-tile
    const int b  = bh / 12;
    const int h  = bh - b*12;
    const size_t hb = (size_t)bh * NN * DD;

    const f32x4 zero4 = {0.f, 0.f, 0.f, 0.f};

    // Q B-frags (pre-scaled by QSCALE) for 2 q-groups of 16
    bf16x8 qf0[2], qf1[2];
    #pragma unroll
    for (int qg = 0; qg < 2; ++qg) {
        const int qrow = bq*64 + w*32 + qg*16 + lc;
        qf0[qg] = *(const bf16x8*)(Q + hb + (size_t)qrow*DD +      quad*8);
        qf1[qg] = *(const bf16x8*)(Q + hb + (size_t)qrow*DD + 32 + quad*8);
    }

    f32x4 o[2][4];
    #pragma unroll
    for (int qg = 0; qg < 2; ++qg)
        #pragma unroll
        for (int dj = 0; dj < 4; ++dj) o[qg][dj] = zero4;
    float lsum[2] = {0.f, 0.f};

    // staging: 128 threads, srow = tid>>1 (64 rows/half), sc = tid&1
    // Each thread stages 64 B (4 x 16B chunks) per half for K and V.
    // K: chunks 4sc+i natural.  V: permuted key-blocks 4sc+i built from
    // contiguous loads L0..L3 (keys kb+0..7 / +8..15 / +16..23 / +24..31,
    // kb = 32*sc): blk(4sc)={L0.lo,L2.lo} blk(4sc+1)={L0.hi,L2.hi}
    //             blk(4sc+2)={L1.lo,L3.lo} blk(4sc+3)={L1.hi,L3.hi}
    const int srow = tid >> 1;
    const int sc = tid & 1;
    const unsigned short* kbase = K + hb + (size_t)srow*DD + sc*32;
    const unsigned short* vbase = Vt_g + hb + (size_t)srow*NN + sc*32;
    const int sw = srow & 7;
    int coff[4];
    #pragma unroll
    for (int i = 0; i < 4; ++i) coff[i] = ((4*sc + i) ^ sw) * 8;
    const int so = srow * 64;

    // frag-read swizzled chunk offsets (same for both halves)
    const int chq0 = ((    quad) ^ x7) * 8;
    const int chq1 = ((4 + quad) ^ x7) * 8;

    auto loadt = [&](KVT& R, int kt) {
        #pragma unroll
        for (int hf = 0; hf < 2; ++hf) {
            const unsigned short* kp = kbase + ((size_t)kt*128 + 64*hf)*DD;
            const unsigned short* vp = vbase + kt*128 + 64*hf;
            #pragma unroll
            for (int i = 0; i < 4; ++i) {
                R.k[hf][i] = *(const u16x8*)(kp + i*8);
                R.v[hf][i] = *(const u16x8*)(vp + i*8);
            }
        }
    };

    auto step = [&](KVT& CUR, KVT& NXT, int kt) {
        // bar A: all waves finished READING the previous tile's LDS.
        asm volatile("s_waitcnt lgkmcnt(0)" ::: "memory");
        __builtin_amdgcn_s_barrier();

        #pragma unroll
        for (int hf = 0; hf < 2; ++hf) {
            const int hb4 = hf*4096 + so;
            *(u16x8*)&Ks[hb4 + coff[0]] = CUR.k[hf][0];
            *(u16x8*)&Ks[hb4 + coff[1]] = CUR.k[hf][1];
            *(u16x8*)&Ks[hb4 + coff[2]] = CUR.k[hf][2];
            *(u16x8*)&Ks[hb4 + coff[3]] = CUR.k[hf][3];
            u16x8 w0 = __builtin_shufflevector(CUR.v[hf][0], CUR.v[hf][2], 0,1,2,3, 8,9,10,11);
            u16x8 w1 = __builtin_shufflevector(CUR.v[hf][0], CUR.v[hf][2], 4,5,6,7, 12,13,14,15);
            u16x8 w2 = __builtin_shufflevector(CUR.v[hf][1], CUR.v[hf][3], 0,1,2,3, 8,9,10,11);
            u16x8 w3 = __builtin_shufflevector(CUR.v[hf][1], CUR.v[hf][3], 4,5,6,7, 12,13,14,15);
            *(u16x8*)&Vt[hb4 + coff[0]] = w0;
            *(u16x8*)&Vt[hb4 + coff[1]] = w1;
            *(u16x8*)&Vt[hb4 + coff[2]] = w2;
            *(u16x8*)&Vt[hb4 + coff[3]] = w3;
        }

        // issue tile kt+1's global loads NOW — they fly under the compute
        if (kt + 1 < NN/128) loadt(NXT, kt + 1);

        // bar B: ds_writes visible to all waves; NO vmcnt drain.
        asm volatile("s_waitcnt lgkmcnt(0)" ::: "memory");
        __builtin_amdgcn_s_barrier();
        __builtin_amdgcn_sched_barrier(0);

        #pragma unroll
        for (int hf = 0; hf < 2; ++hf) {
            const int base = hf * 4096;

            // S^T = K Q^T : 4 key-frags x 2 k-steps x 2 q-groups.
            // Each kf ds_read now feeds TWO MFMAs (the reuse win).
            f32x4 st[2][4];
            #pragma unroll
            for (int jf = 0; jf < 4; ++jf) {
                bf16x8 kf0 = *(const bf16x8*)&Ks[base + (16*jf + lc)*64 + chq0];
                bf16x8 kf1 = *(const bf16x8*)&Ks[base + (16*jf + lc)*64 + chq1];
                #pragma unroll
                for (int qg = 0; qg < 2; ++qg) {
                    f32x4 acc0 = MFMA(kf0, qf0[qg], zero4);
                    st[qg][jf] = MFMA(kf1, qf1[qg], acc0);
                }
            }

            // P = exp2(S^T) stays in registers (sigma-ordered packing)
            bf16x8 pf0[2], pf1[2];
            #pragma unroll
            for (int qg = 0; qg < 2; ++qg) {
                f32x4 ev[4];
                #pragma unroll
                for (int jf = 0; jf < 4; ++jf) {
                    ev[jf][0] = __builtin_amdgcn_exp2f(st[qg][jf][0]);
                    ev[jf][1] = __builtin_amdgcn_exp2f(st[qg][jf][1]);
                    ev[jf][2] = __builtin_amdgcn_exp2f(st[qg][jf][2]);
                    ev[jf][3] = __builtin_amdgcn_exp2f(st[qg][jf][3]);
                    lsum[qg] += (ev[jf][0] + ev[jf][1]) + (ev[jf][2] + ev[jf][3]);
                }
                u16x8 p0, p1;
                #pragma unroll
                for (int r = 0; r < 4; ++r) {
                    p0[r]     = f2bf(ev[0][r]);
                    p0[r + 4] = f2bf(ev[1][r]);
                    p1[r]     = f2bf(ev[2][r]);
                    p1[r + 4] = f2bf(ev[3][r]);
                }
                pf0[qg] = as_bf16x8(p0);
                pf1[qg] = as_bf16x8(p1);
            }

            // O^T += V^T P^T (each vf ds_read feeds TWO MFMAs)
            #pragma unroll
            for (int dj = 0; dj < 4; ++dj) {
                bf16x8 vf0 = *(const bf16x8*)&Vt[base + (16*dj + lc)*64 + chq0];
                bf16x8 vf1 = *(const bf16x8*)&Vt[base + (16*dj + lc)*64 + chq1];
                #pragma unroll
                for (int qg = 0; qg < 2; ++qg) {
                    o[qg][dj] = MFMA(vf0, pf0[qg], o[qg][dj]);
                    o[qg][dj] = MFMA(vf1, pf1[qg], o[qg][dj]);
                }
            }
        }
    };

    KVT ra, rb;
    loadt(ra, 0);
    for (int it = 0; it < NN/256; ++it) {   // 8 iters, 2 tiles each
        step(ra, rb, 2*it);
        step(rb, ra, 2*it + 1);
    }

    // final denominator + store, per q-group
    #pragma unroll
    for (int qg = 0; qg < 2; ++qg) {
        float s = lsum[qg];
        s += __shfl_xor(s, 16);
        s += __shfl_xor(s, 32);
        const float inv = 1.f / s;
        const int n = bq*64 + w*32 + qg*16 + lc;
        #pragma unroll
        for (int dj = 0; dj < 4; ++dj) {
            ushort4 pk;
            pk.x = f2bf(o[qg][dj][0] * inv);
            pk.y = f2bf(o[qg][dj][1] * inv);
            pk.z = f2bf(o[qg][dj][2] * inv);
            pk.w = f2bf(o[qg][dj][3] * inv);
            *(ushort4*)&ctx[((size_t)(b*NN + n))*EE + h*DD + 16*dj + quad*4] = pk;
        }
    }
}

// ---------------------------------------------------------------------------
extern "C" void kernel_launch(void* const* d_in, const int* in_sizes, int n_in,
                              void* d_out, int out_size, void* d_ws, size_t ws_size,
                              hipStream_t stream)
{
    const float* x     = (const float*)d_in[0];
    const float* w_qkv = (const float*)d_in[1];
    const float* b_qkv = (const float*)d_in[2];
    const float* w_o   = (const float*)d_in[3];
    const float* b_o   = (const float*)d_in[4];
    float* out = (float*)d_out;

    unsigned short* wsu = (unsigned short*)d_ws;
    const size_t XB = (size_t)MM * EE;
    const size_t WQ = (size_t)E3 * EE;
    const size_t WO = (size_t)EE * EE;
    const size_t HS = (size_t)BB * HH * NN * DD;
    unsigned short* xb   = wsu;
    unsigned short* wqb  = xb  + XB;
    unsigned short* wob  = wqb + WQ;
    unsigned short* qb   = wob + WO;      // [B][H][N][D] (scaled)
    unsigned short* kb   = qb  + HS;      // [B][H][N][D]
    unsigned short* vtb  = kb  + HS;      // [B][H][D][N]
    unsigned short* ctxb = vtb + HS;

    cast3<<<(XB4 + WQ4 + WO4)/256, 256, 0, stream>>>(x, w_qkv, w_o, xb);

    dim3 g1(MM/128, E3/64);    // 32 x 36 = 1152 blocks
    gemm_qkv<<<g1, 256, 0, stream>>>(xb, wqb, b_qkv, qb, kb, vtb);

    attn_mfma<<<768, 128, 0, stream>>>(qb, kb, vtb, ctxb);

    dim3 g3(MM/64, EE/64);     // 64 x 12 = 768 blocks
    gemm_out<<<g3, 256, 0, stream>>>(ctxb, wob, b_o, out);
}